// Round 2
// baseline (434.095 us; speedup 1.0000x reference)
//
#include <hip/hip_runtime.h>
#include <hip/hip_bf16.h>

// Problem constants (match reference)
#define B_  32
#define P_  16
#define S_  256
#define D_  256
#define NG_ 128
#define N_  (B_ * NG_)     // 4096 nodes
#define E_  65536
#define H_  256
#define CAP 128            // per-node in-edge bucket capacity (mean deg=16; P(>128) ~ e^-150)

// ---------------------------------------------------------------------------
// 1) node_x[n,:] = mean_p emb[b, p, gid[b,g], :]   (n = b*NG+g), float4 rows
// ---------------------------------------------------------------------------
__global__ __launch_bounds__(64) void k_node_mean(
    const float* __restrict__ emb, const int* __restrict__ gids,
    float* __restrict__ node_x) {
  const int n = blockIdx.x;            // 0..4095
  const int b = n >> 7;
  const int g = n & (NG_ - 1);
  const int s = gids[b * NG_ + g];
  const int t = threadIdx.x;           // 0..63, one float4 each
  const float4* base = (const float4*)(emb + (size_t)b * (P_ * S_ * D_) + (size_t)s * D_) + t;
  float4 acc = {0.f, 0.f, 0.f, 0.f};
#pragma unroll
  for (int p = 0; p < P_; ++p) {
    float4 v = base[(size_t)p * (S_ * D_ / 4)];
    acc.x += v.x; acc.y += v.y; acc.z += v.z; acc.w += v.w;
  }
  const float inv = 1.0f / P_;
  acc.x *= inv; acc.y *= inv; acc.z *= inv; acc.w *= inv;
  ((float4*)(node_x + (size_t)n * D_))[t] = acc;
}

// ---------------------------------------------------------------------------
// 2) CSR-ish bucket build: cnt[v] = in-degree, bucket[v*CAP + i] = src
// ---------------------------------------------------------------------------
__global__ void k_zero(int* __restrict__ cnt) {
  int i = blockIdx.x * blockDim.x + threadIdx.x;
  if (i < N_) cnt[i] = 0;
}

__global__ void k_build(const int* __restrict__ src, const int* __restrict__ dst,
                        int* __restrict__ cnt, int* __restrict__ bucket) {
  int e = blockIdx.x * blockDim.x + threadIdx.x;
  if (e < E_) {
    int d = dst[e], s = src[e];
    int pos = atomicAdd(&cnt[d], 1);
    if (pos < CAP) bucket[(size_t)d * CAP + pos] = s;
  }
}

__global__ void k_norm(const int* __restrict__ cnt, float* __restrict__ dis) {
  int i = blockIdx.x * blockDim.x + threadIdx.x;
  if (i < N_) dis[i] = rsqrtf((float)(1 + cnt[i]));  // self-loop included
}

// ---------------------------------------------------------------------------
// 3) GEMM h = act(x) @ W  (M=4096,K=256,N=256). x reads are wave-uniform
//    (scalar-cache s_loads); W reads coalesced per column. No LDS, no barrier.
// ---------------------------------------------------------------------------
#define RPB 16
__global__ __launch_bounds__(256) void k_gemm(
    const float* __restrict__ x, const float* __restrict__ W,
    float* __restrict__ out, int apply_relu) {
  const int tid = threadIdx.x;
  const int row0 = blockIdx.x * RPB;
  float acc[RPB];
#pragma unroll
  for (int r = 0; r < RPB; ++r) acc[r] = 0.f;
  for (int k = 0; k < D_; k += 4) {
    const float w0 = W[(size_t)(k + 0) * H_ + tid];
    const float w1 = W[(size_t)(k + 1) * H_ + tid];
    const float w2 = W[(size_t)(k + 2) * H_ + tid];
    const float w3 = W[(size_t)(k + 3) * H_ + tid];
#pragma unroll
    for (int r = 0; r < RPB; ++r) {
      float4 xv = *(const float4*)(x + (size_t)(row0 + r) * D_ + k);  // uniform
      if (apply_relu) {
        xv.x = fmaxf(xv.x, 0.f); xv.y = fmaxf(xv.y, 0.f);
        xv.z = fmaxf(xv.z, 0.f); xv.w = fmaxf(xv.w, 0.f);
      }
      acc[r] = fmaf(xv.x, w0, fmaf(xv.y, w1, fmaf(xv.z, w2, fmaf(xv.w, w3, acc[r]))));
    }
  }
#pragma unroll
  for (int r = 0; r < RPB; ++r) out[(size_t)(row0 + r) * H_ + tid] = acc[r];
}

// ---------------------------------------------------------------------------
// 4) Gather-aggregate: out[v,t] = bias[t] + dis[v]^2*h[v,t]
//                               + sum_i dis[u_i]*dis[v]*h[u_i,t]
// ---------------------------------------------------------------------------
__global__ __launch_bounds__(256) void k_agg(
    const float* __restrict__ h, const float* __restrict__ bias,
    const float* __restrict__ dis, const int* __restrict__ cnt,
    const int* __restrict__ bucket, float* __restrict__ out) {
  const int v = blockIdx.x;
  const int t = threadIdx.x;
  const float dv = dis[v];
  int m = cnt[v]; if (m > CAP) m = CAP;
  float acc = bias[t] + dv * dv * h[(size_t)v * H_ + t];
  const int* bk = bucket + (size_t)v * CAP;
  for (int i = 0; i < m; ++i) {
    const int u = bk[i];                       // wave-uniform
    acc = fmaf(dv * dis[u], h[(size_t)u * H_ + t], acc);
  }
  out[(size_t)v * H_ + t] = acc;
}

// ---------------------------------------------------------------------------
// 5) Global mean pool
// ---------------------------------------------------------------------------
__global__ __launch_bounds__(256) void k_pool(
    const float* __restrict__ x2, float* __restrict__ out) {
  const int b = blockIdx.x;
  const int t = threadIdx.x;
  float acc = 0.f;
  for (int g = 0; g < NG_; ++g) acc += x2[(size_t)((b << 7) + g) * H_ + t];
  out[(size_t)b * H_ + t] = acc * (1.0f / NG_);
}

extern "C" void kernel_launch(void* const* d_in, const int* in_sizes, int n_in,
                              void* d_out, int out_size, void* d_ws, size_t ws_size,
                              hipStream_t stream) {
  const float* emb  = (const float*)d_in[0];   // [B,P,S,D]
  const int*   gids = (const int*)d_in[1];     // [B,NG]
  const int*   eidx = (const int*)d_in[2];     // [2,E]
  const float* W1   = (const float*)d_in[3];
  const float* b1   = (const float*)d_in[4];
  const float* W2   = (const float*)d_in[5];
  const float* b2   = (const float*)d_in[6];
  float* out = (float*)d_out;

  const int* src = eidx;        // edge_index[0]
  const int* dst = eidx + E_;   // edge_index[1]

  // Workspace layout
  float* ws = (float*)d_ws;
  float* node_x = ws;                          // 4 MB (N*D)
  float* hbuf   = node_x + (size_t)N_ * D_;    // 4 MB (N*H)
  float* x1     = hbuf   + (size_t)N_ * H_;    // 4 MB
  float* x2     = x1     + (size_t)N_ * H_;    // 4 MB
  float* dis    = x2     + (size_t)N_ * H_;    // 16 KB
  int*   cnt    = (int*)(dis + N_);            // 16 KB
  int*   bucket = cnt + N_;                    // 2 MB (N*CAP)

  // 1) node features
  k_node_mean<<<N_, 64, 0, stream>>>(emb, gids, node_x);

  // 2) adjacency buckets + norms
  k_zero<<<(N_ + 255) / 256, 256, 0, stream>>>(cnt);
  k_build<<<(E_ + 255) / 256, 256, 0, stream>>>(src, dst, cnt, bucket);
  k_norm<<<(N_ + 255) / 256, 256, 0, stream>>>(cnt, dis);

  // 3) layer 1
  k_gemm<<<N_ / RPB, 256, 0, stream>>>(node_x, W1, hbuf, 0);
  k_agg<<<N_, 256, 0, stream>>>(hbuf, b1, dis, cnt, bucket, x1);

  // 4) layer 2 (relu fused into GEMM x-load)
  k_gemm<<<N_ / RPB, 256, 0, stream>>>(x1, W2, hbuf, 1);
  k_agg<<<N_, 256, 0, stream>>>(hbuf, b2, dis, cnt, bucket, x2);

  // 5) pool
  k_pool<<<B_, 256, 0, stream>>>(x2, out);
}

// Round 3
// 249.307 us; speedup vs baseline: 1.7412x; 1.7412x over previous
//
#include <hip/hip_runtime.h>
#include <hip/hip_bf16.h>

// Problem constants (match reference)
#define B_  32
#define P_  16
#define S_  256
#define D_  256
#define NG_ 128
#define N_  (B_ * NG_)     // 4096 nodes
#define E_  65536
#define H_  256
#define CAP 128            // per-node in-edge bucket capacity (mean deg=16)

// ---------------------------------------------------------------------------
// 1) node_x[n,:] = mean_p emb[b, p, gid[b,g], :]   (n = b*NG+g), float4 rows
// ---------------------------------------------------------------------------
__global__ __launch_bounds__(64) void k_node_mean(
    const float* __restrict__ emb, const int* __restrict__ gids,
    float* __restrict__ node_x) {
  const int n = blockIdx.x;
  const int b = n >> 7;
  const int g = n & (NG_ - 1);
  const int s = gids[b * NG_ + g];
  const int t = threadIdx.x;           // one float4 each
  const float4* base = (const float4*)(emb + (size_t)b * (P_ * S_ * D_) + (size_t)s * D_) + t;
  float4 acc = {0.f, 0.f, 0.f, 0.f};
#pragma unroll
  for (int p = 0; p < P_; ++p) {
    float4 v = base[(size_t)p * (S_ * D_ / 4)];
    acc.x += v.x; acc.y += v.y; acc.z += v.z; acc.w += v.w;
  }
  const float inv = 1.0f / P_;
  acc.x *= inv; acc.y *= inv; acc.z *= inv; acc.w *= inv;
  ((float4*)(node_x + (size_t)n * D_))[t] = acc;
}

// ---------------------------------------------------------------------------
// 2) adjacency buckets: cnt[v] = in-degree (no self-loop), bucket[v*CAP+i]=src
// ---------------------------------------------------------------------------
__global__ void k_zero(int* __restrict__ cnt) {
  int i = blockIdx.x * blockDim.x + threadIdx.x;
  if (i < N_) cnt[i] = 0;
}

__global__ void k_build(const int* __restrict__ src, const int* __restrict__ dst,
                        int* __restrict__ cnt, int* __restrict__ bucket) {
  int e = blockIdx.x * blockDim.x + threadIdx.x;
  if (e < E_) {
    int d = dst[e], s = src[e];
    int pos = atomicAdd(&cnt[d], 1);
    if (pos < CAP) bucket[(size_t)d * CAP + pos] = s;
  }
}

// ---------------------------------------------------------------------------
// 3) Tiled fp32 GEMM: out = x @ W   (M=4096, K=256, N=256)
//    BM=64 BN=64 BK=32, 256 thr (16x16), 4x4 acc/thread, LDS staged,
//    register prefetch of next K-chunk. LDS stride +4 pad (16B-aligned,
//    breaks the k-major bank collision).
// ---------------------------------------------------------------------------
#define BM 64
#define BN 64
#define BK 32
#define LDA (BM + 4)
#define LDB (BN + 4)
__global__ __launch_bounds__(256) void k_gemm(
    const float* __restrict__ x, const float* __restrict__ W,
    float* __restrict__ out) {
  __shared__ float As[BK][LDA];
  __shared__ float Bs[BK][LDB];
  const int tid = threadIdx.x;
  const int m0 = (blockIdx.x >> 2) * BM;
  const int n0 = (blockIdx.x & 3) * BN;
  const int tx = tid & 15, ty = tid >> 4;
  // staging coords
  const int ar = tid >> 3;            // 0..31
  const int ak = (tid & 7) * 4;       // 0,4,..,28
  const int bk = tid >> 4;            // 0..15
  const int bn = (tid & 15) * 4;      // 0,4,..,60

  float acc[4][4] = {};
  // prefetch chunk 0
  float4 a0 = *(const float4*)(x + (size_t)(m0 + ar) * D_ + ak);
  float4 a1 = *(const float4*)(x + (size_t)(m0 + ar + 32) * D_ + ak);
  float4 b0 = *(const float4*)(W + (size_t)bk * H_ + n0 + bn);
  float4 b1 = *(const float4*)(W + (size_t)(bk + 16) * H_ + n0 + bn);

  for (int kk = 0; kk < D_; kk += BK) {
    __syncthreads();   // protect previous chunk's LDS reads
    As[ak + 0][ar] = a0.x; As[ak + 1][ar] = a0.y;
    As[ak + 2][ar] = a0.z; As[ak + 3][ar] = a0.w;
    As[ak + 0][ar + 32] = a1.x; As[ak + 1][ar + 32] = a1.y;
    As[ak + 2][ar + 32] = a1.z; As[ak + 3][ar + 32] = a1.w;
    *(float4*)&Bs[bk][bn] = b0;
    *(float4*)&Bs[bk + 16][bn] = b1;
    __syncthreads();
    if (kk + BK < D_) {  // prefetch next chunk (hidden under compute)
      a0 = *(const float4*)(x + (size_t)(m0 + ar) * D_ + kk + BK + ak);
      a1 = *(const float4*)(x + (size_t)(m0 + ar + 32) * D_ + kk + BK + ak);
      b0 = *(const float4*)(W + (size_t)(kk + BK + bk) * H_ + n0 + bn);
      b1 = *(const float4*)(W + (size_t)(kk + BK + bk + 16) * H_ + n0 + bn);
    }
#pragma unroll
    for (int k = 0; k < BK; ++k) {
      const float4 a = *(const float4*)&As[k][ty * 4];
      const float4 b = *(const float4*)&Bs[k][tx * 4];
      acc[0][0] = fmaf(a.x, b.x, acc[0][0]); acc[0][1] = fmaf(a.x, b.y, acc[0][1]);
      acc[0][2] = fmaf(a.x, b.z, acc[0][2]); acc[0][3] = fmaf(a.x, b.w, acc[0][3]);
      acc[1][0] = fmaf(a.y, b.x, acc[1][0]); acc[1][1] = fmaf(a.y, b.y, acc[1][1]);
      acc[1][2] = fmaf(a.y, b.z, acc[1][2]); acc[1][3] = fmaf(a.y, b.w, acc[1][3]);
      acc[2][0] = fmaf(a.z, b.x, acc[2][0]); acc[2][1] = fmaf(a.z, b.y, acc[2][1]);
      acc[2][2] = fmaf(a.z, b.z, acc[2][2]); acc[2][3] = fmaf(a.z, b.w, acc[2][3]);
      acc[3][0] = fmaf(a.w, b.x, acc[3][0]); acc[3][1] = fmaf(a.w, b.y, acc[3][1]);
      acc[3][2] = fmaf(a.w, b.z, acc[3][2]); acc[3][3] = fmaf(a.w, b.w, acc[3][3]);
    }
  }
#pragma unroll
  for (int i = 0; i < 4; ++i) {
    float4 v = {acc[i][0], acc[i][1], acc[i][2], acc[i][3]};
    *(float4*)(out + (size_t)(m0 + ty * 4 + i) * H_ + n0 + tx * 4) = v;
  }
}

// ---------------------------------------------------------------------------
// 4) Gather-aggregate (+ fused symmetric norm, + optional ReLU on output):
//    out[v,t] = act( bias[t] + dis(v)^2*h[v,t] + sum_i dis(u_i)*dis(v)*h[u_i,t] )
//    dis(w) = rsqrt(1 + cnt[w])
// ---------------------------------------------------------------------------
template <int RELU>
__global__ __launch_bounds__(256) void k_agg(
    const float* __restrict__ h, const float* __restrict__ bias,
    const int* __restrict__ cnt, const int* __restrict__ bucket,
    float* __restrict__ out) {
  const int v = blockIdx.x;
  const int t = threadIdx.x;
  const int deg = cnt[v];
  const float dv = rsqrtf(1.0f + (float)deg);
  int m = deg > CAP ? CAP : deg;
  float acc = bias[t] + dv * dv * h[(size_t)v * H_ + t];
  const int* bk = bucket + (size_t)v * CAP;
#pragma unroll 4
  for (int i = 0; i < m; ++i) {
    const int u = bk[i];
    const float du = rsqrtf(1.0f + (float)cnt[u]);
    acc = fmaf(dv * du, h[(size_t)u * H_ + t], acc);
  }
  if (RELU) acc = fmaxf(acc, 0.f);
  out[(size_t)v * H_ + t] = acc;
}

// ---------------------------------------------------------------------------
// 5) Global mean pool
// ---------------------------------------------------------------------------
__global__ __launch_bounds__(256) void k_pool(
    const float* __restrict__ x2, float* __restrict__ out) {
  const int b = blockIdx.x;
  const int t = threadIdx.x;
  float acc = 0.f;
  for (int g = 0; g < NG_; ++g) acc += x2[(size_t)((b << 7) + g) * H_ + t];
  out[(size_t)b * H_ + t] = acc * (1.0f / NG_);
}

extern "C" void kernel_launch(void* const* d_in, const int* in_sizes, int n_in,
                              void* d_out, int out_size, void* d_ws, size_t ws_size,
                              hipStream_t stream) {
  const float* emb  = (const float*)d_in[0];
  const int*   gids = (const int*)d_in[1];
  const int*   eidx = (const int*)d_in[2];
  const float* W1   = (const float*)d_in[3];
  const float* b1   = (const float*)d_in[4];
  const float* W2   = (const float*)d_in[5];
  const float* b2   = (const float*)d_in[6];
  float* out = (float*)d_out;

  const int* src = eidx;
  const int* dst = eidx + E_;

  // Workspace layout
  float* ws = (float*)d_ws;
  float* node_x = ws;                          // 4 MB
  float* hbuf   = node_x + (size_t)N_ * D_;    // 4 MB
  float* x1     = hbuf   + (size_t)N_ * H_;    // 4 MB
  float* x2     = x1     + (size_t)N_ * H_;    // 4 MB
  int*   cnt    = (int*)(x2 + (size_t)N_ * H_);// 16 KB
  int*   bucket = cnt + N_;                    // 2 MB

  // 1) node features
  k_node_mean<<<N_, 64, 0, stream>>>(emb, gids, node_x);

  // 2) adjacency buckets
  k_zero<<<(N_ + 255) / 256, 256, 0, stream>>>(cnt);
  k_build<<<(E_ + 255) / 256, 256, 0, stream>>>(src, dst, cnt, bucket);

  // 3) layer 1 (ReLU fused into agg epilogue)
  k_gemm<<<(N_ / BM) * (H_ / BN), 256, 0, stream>>>(node_x, W1, hbuf);
  k_agg<1><<<N_, 256, 0, stream>>>(hbuf, b1, cnt, bucket, x1);

  // 4) layer 2
  k_gemm<<<(N_ / BM) * (H_ / BN), 256, 0, stream>>>(x1, W2, hbuf);
  k_agg<0><<<N_, 256, 0, stream>>>(hbuf, b2, cnt, bucket, x2);

  // 5) pool
  k_pool<<<B_, 256, 0, stream>>>(x2, out);
}

// Round 4
// 247.577 us; speedup vs baseline: 1.7534x; 1.0070x over previous
//
#include <hip/hip_runtime.h>
#include <hip/hip_bf16.h>

// Problem constants (match reference)
#define B_  32
#define P_  16
#define S_  256
#define D_  256
#define NG_ 128
#define N_  (B_ * NG_)     // 4096 nodes
#define E_  65536
#define H_  256
#define CAP 128            // per-node in-edge bucket capacity (mean deg 16, Poisson)

// ---------------------------------------------------------------------------
// 1) node_x[n,:] = mean_p emb[b, p, gid[b,g], :]   (n = b*NG+g), float4 rows
// ---------------------------------------------------------------------------
__global__ __launch_bounds__(64) void k_node_mean(
    const float* __restrict__ emb, const int* __restrict__ gids,
    float* __restrict__ node_x) {
  const int n = blockIdx.x;
  const int b = n >> 7;
  const int g = n & (NG_ - 1);
  const int s = gids[b * NG_ + g];
  const int t = threadIdx.x;           // one float4 each
  const float4* base = (const float4*)(emb + (size_t)b * (P_ * S_ * D_) + (size_t)s * D_) + t;
  float4 acc = {0.f, 0.f, 0.f, 0.f};
#pragma unroll
  for (int p = 0; p < P_; ++p) {
    float4 v = base[(size_t)p * (S_ * D_ / 4)];
    acc.x += v.x; acc.y += v.y; acc.z += v.z; acc.w += v.w;
  }
  const float inv = 1.0f / P_;
  acc.x *= inv; acc.y *= inv; acc.z *= inv; acc.w *= inv;
  ((float4*)(node_x + (size_t)n * D_))[t] = acc;
}

// ---------------------------------------------------------------------------
// 2) adjacency buckets: cnt[v] = in-degree (no self-loop), bucket[v*CAP+i]=src
// ---------------------------------------------------------------------------
__global__ void k_zero(int* __restrict__ cnt) {
  int i = blockIdx.x * blockDim.x + threadIdx.x;
  if (i < N_) cnt[i] = 0;
}

__global__ void k_build(const int* __restrict__ src, const int* __restrict__ dst,
                        int* __restrict__ cnt, int* __restrict__ bucket) {
  int e = blockIdx.x * blockDim.x + threadIdx.x;
  if (e < E_) {
    int d = dst[e], s = src[e];
    int pos = atomicAdd(&cnt[d], 1);
    if (pos < CAP) bucket[(size_t)d * CAP + pos] = s;
  }
}

// ---------------------------------------------------------------------------
// 3) Tiled fp32 GEMM: out = x @ W   (M=4096, K=256, N=256)
//    BM=32 BN=64 BK=32, 256 thr, acc 2x4/thread, grid 512 (2 blocks/CU),
//    register prefetch of next K-chunk.
// ---------------------------------------------------------------------------
#define BM 32
#define BN 64
#define BK 32
#define LDA (BM + 2)   // even -> float2-aligned compute reads
#define LDB (BN + 4)   // mult of 4 -> float4-aligned
__global__ __launch_bounds__(256) void k_gemm(
    const float* __restrict__ x, const float* __restrict__ W,
    float* __restrict__ out) {
  __shared__ float As[BK][LDA];
  __shared__ float Bs[BK][LDB];
  const int tid = threadIdx.x;
  const int m0 = (blockIdx.x >> 2) * BM;
  const int n0 = (blockIdx.x & 3) * BN;
  // staging coords
  const int ar  = tid >> 3;           // 0..31  (row within tile)
  const int ak  = (tid & 7) * 4;      // 0,4,..,28
  const int bkr = tid >> 4;           // 0..15
  const int bn  = (tid & 15) * 4;     // 0,4,..,60
  // compute coords
  const int tx = tid & 15;            // 4 cols each
  const int ty = tid >> 4;            // 2 rows each

  float acc[2][4] = {};
  float4 a0 = *(const float4*)(x + (size_t)(m0 + ar) * D_ + ak);
  float4 b0 = *(const float4*)(W + (size_t)bkr * H_ + n0 + bn);
  float4 b1 = *(const float4*)(W + (size_t)(bkr + 16) * H_ + n0 + bn);

  for (int kk = 0; kk < D_; kk += BK) {
    __syncthreads();
    As[ak + 0][ar] = a0.x; As[ak + 1][ar] = a0.y;
    As[ak + 2][ar] = a0.z; As[ak + 3][ar] = a0.w;
    *(float4*)&Bs[bkr][bn] = b0;
    *(float4*)&Bs[bkr + 16][bn] = b1;
    __syncthreads();
    if (kk + BK < D_) {
      a0 = *(const float4*)(x + (size_t)(m0 + ar) * D_ + kk + BK + ak);
      b0 = *(const float4*)(W + (size_t)(kk + BK + bkr) * H_ + n0 + bn);
      b1 = *(const float4*)(W + (size_t)(kk + BK + bkr + 16) * H_ + n0 + bn);
    }
#pragma unroll
    for (int k = 0; k < BK; ++k) {
      const float2 a = *(const float2*)&As[k][ty * 2];
      const float4 b = *(const float4*)&Bs[k][tx * 4];
      acc[0][0] = fmaf(a.x, b.x, acc[0][0]); acc[0][1] = fmaf(a.x, b.y, acc[0][1]);
      acc[0][2] = fmaf(a.x, b.z, acc[0][2]); acc[0][3] = fmaf(a.x, b.w, acc[0][3]);
      acc[1][0] = fmaf(a.y, b.x, acc[1][0]); acc[1][1] = fmaf(a.y, b.y, acc[1][1]);
      acc[1][2] = fmaf(a.y, b.z, acc[1][2]); acc[1][3] = fmaf(a.y, b.w, acc[1][3]);
    }
  }
#pragma unroll
  for (int i = 0; i < 2; ++i) {
    float4 v = {acc[i][0], acc[i][1], acc[i][2], acc[i][3]};
    *(float4*)(out + (size_t)(m0 + ty * 2 + i) * H_ + n0 + tx * 4) = v;
  }
}

// ---------------------------------------------------------------------------
// 4) Gather-aggregate, two-phase:
//    phase 1: stage neighbor ids + prefolded norms (dv*du) into LDS
//    phase 2: 4-way unrolled gather -> 4 independent in-flight row loads
//    out[v,t] = act( bias[t] + dv^2*h[v,t] + sum_i (dv*du_i)*h[u_i,t] )
// ---------------------------------------------------------------------------
template <int RELU>
__global__ __launch_bounds__(256) void k_agg(
    const float* __restrict__ h, const float* __restrict__ bias,
    const int* __restrict__ cnt, const int* __restrict__ bucket,
    float* __restrict__ out) {
  __shared__ int   us[CAP];
  __shared__ float fs[CAP];
  const int v = blockIdx.x;
  const int t = threadIdx.x;
  const int deg = cnt[v];
  const float dv = rsqrtf(1.0f + (float)deg);
  const int m = deg > CAP ? CAP : deg;
  if (t < m) {                       // t < CAP(=128) implied
    const int u = bucket[(size_t)v * CAP + t];
    us[t] = u;
    fs[t] = dv * rsqrtf(1.0f + (float)cnt[u]);
  }
  __syncthreads();
  float acc = bias[t] + dv * dv * h[(size_t)v * H_ + t];
  int i = 0;
  for (; i + 4 <= m; i += 4) {
    const int u0 = us[i], u1 = us[i + 1], u2 = us[i + 2], u3 = us[i + 3];
    const float f0 = fs[i], f1 = fs[i + 1], f2 = fs[i + 2], f3 = fs[i + 3];
    const float h0 = h[(size_t)u0 * H_ + t];
    const float h1 = h[(size_t)u1 * H_ + t];
    const float h2 = h[(size_t)u2 * H_ + t];
    const float h3 = h[(size_t)u3 * H_ + t];
    acc = fmaf(f0, h0, acc); acc = fmaf(f1, h1, acc);
    acc = fmaf(f2, h2, acc); acc = fmaf(f3, h3, acc);
  }
  for (; i < m; ++i) acc = fmaf(fs[i], h[(size_t)us[i] * H_ + t], acc);
  if (RELU) acc = fmaxf(acc, 0.f);
  out[(size_t)v * H_ + t] = acc;
}

// ---------------------------------------------------------------------------
// 5) Global mean pool
// ---------------------------------------------------------------------------
__global__ __launch_bounds__(256) void k_pool(
    const float* __restrict__ x2, float* __restrict__ out) {
  const int b = blockIdx.x;
  const int t = threadIdx.x;
  float acc = 0.f;
#pragma unroll 8
  for (int g = 0; g < NG_; ++g) acc += x2[(size_t)((b << 7) + g) * H_ + t];
  out[(size_t)b * H_ + t] = acc * (1.0f / NG_);
}

extern "C" void kernel_launch(void* const* d_in, const int* in_sizes, int n_in,
                              void* d_out, int out_size, void* d_ws, size_t ws_size,
                              hipStream_t stream) {
  const float* emb  = (const float*)d_in[0];
  const int*   gids = (const int*)d_in[1];
  const int*   eidx = (const int*)d_in[2];
  const float* W1   = (const float*)d_in[3];
  const float* b1   = (const float*)d_in[4];
  const float* W2   = (const float*)d_in[5];
  const float* b2   = (const float*)d_in[6];
  float* out = (float*)d_out;

  const int* src = eidx;
  const int* dst = eidx + E_;

  // Workspace layout
  float* ws = (float*)d_ws;
  float* node_x = ws;                          // 4 MB
  float* hbuf   = node_x + (size_t)N_ * D_;    // 4 MB
  float* x1     = hbuf   + (size_t)N_ * H_;    // 4 MB
  float* x2     = x1     + (size_t)N_ * H_;    // 4 MB
  int*   cnt    = (int*)(x2 + (size_t)N_ * H_);// 16 KB
  int*   bucket = cnt + N_;                    // 2 MB

  // 1) node features
  k_node_mean<<<N_, 64, 0, stream>>>(emb, gids, node_x);

  // 2) adjacency buckets
  k_zero<<<(N_ + 255) / 256, 256, 0, stream>>>(cnt);
  k_build<<<(E_ + 255) / 256, 256, 0, stream>>>(src, dst, cnt, bucket);

  // 3) layer 1 (ReLU fused into agg epilogue)
  k_gemm<<<(N_ / BM) * (H_ / BN), 256, 0, stream>>>(node_x, W1, hbuf);
  k_agg<1><<<N_, 256, 0, stream>>>(hbuf, b1, cnt, bucket, x1);

  // 4) layer 2
  k_gemm<<<(N_ / BM) * (H_ / BN), 256, 0, stream>>>(x1, W2, hbuf);
  k_agg<0><<<N_, 256, 0, stream>>>(hbuf, b2, cnt, bucket, x2);

  // 5) pool
  k_pool<<<B_, 256, 0, stream>>>(x2, out);
}

// Round 5
// 247.369 us; speedup vs baseline: 1.7548x; 1.0008x over previous
//
#include <hip/hip_runtime.h>
#include <hip/hip_bf16.h>

// Problem constants (match reference)
#define B_  32
#define P_  16
#define S_  256
#define D_  256
#define NG_ 128
#define N_  (B_ * NG_)     // 4096 nodes
#define E_  65536
#define H_  256
#define CAP 64             // in-degree cap: deg ~ Poisson(16), P(deg>64) < 1e-19
#define BG  4              // graphs per block in k_out
#define UC  256            // u-chunk in k_out

// ---------------------------------------------------------------------------
// K1: node_x[n,:] = mean_p emb[b,p,gid[b,g],:]  + zero cnt/w2/out
// ---------------------------------------------------------------------------
__global__ __launch_bounds__(64) void k_node_mean(
    const float* __restrict__ emb, const int* __restrict__ gids,
    float* __restrict__ node_x, int* __restrict__ cnt,
    float* __restrict__ w2, float* __restrict__ outp) {
  const int n = blockIdx.x;
  const int t = threadIdx.x;
  if (t == 0) cnt[n] = 0;
  const int gt = (n << 6) + t;                 // 0..262143
  if (gt < B_ * N_) w2[gt] = 0.f;              // 131072 floats
  if (gt < B_ * H_) outp[gt] = 0.f;            // 8192 floats
  const int b = n >> 7;
  const int g = n & (NG_ - 1);
  const int s = gids[b * NG_ + g];
  const float4* base = (const float4*)(emb + (size_t)b * (P_ * S_ * D_) + (size_t)s * D_) + t;
  float4 acc = {0.f, 0.f, 0.f, 0.f};
#pragma unroll
  for (int p = 0; p < P_; ++p) {
    float4 v = base[(size_t)p * (S_ * D_ / 4)];
    acc.x += v.x; acc.y += v.y; acc.z += v.z; acc.w += v.w;
  }
  const float inv = 1.0f / P_;
  acc.x *= inv; acc.y *= inv; acc.z *= inv; acc.w *= inv;
  ((float4*)(node_x + (size_t)n * D_))[t] = acc;
}

// ---------------------------------------------------------------------------
// K2: adjacency buckets: cnt[v]=in-degree (no self-loop), bucket[v*CAP+i]=src
// ---------------------------------------------------------------------------
__global__ void k_build(const int* __restrict__ src, const int* __restrict__ dst,
                        int* __restrict__ cnt, int* __restrict__ bucket) {
  int e = blockIdx.x * blockDim.x + threadIdx.x;
  if (e < E_) {
    int d = dst[e], s = src[e];
    int pos = atomicAdd(&cnt[d], 1);
    if (pos < CAP) bucket[(size_t)d * CAP + pos] = s;
  }
}

// ---------------------------------------------------------------------------
// K3/K5: tiled fp32 GEMM out = x @ W  (M=4096,K=256,N=256), BM=32 BN=64 BK=32
// ---------------------------------------------------------------------------
#define BM 32
#define BN 64
#define BK 32
#define LDA (BM + 2)
#define LDB (BN + 4)
__global__ __launch_bounds__(256) void k_gemm(
    const float* __restrict__ x, const float* __restrict__ W,
    float* __restrict__ out) {
  __shared__ float As[BK][LDA];
  __shared__ float Bs[BK][LDB];
  const int tid = threadIdx.x;
  const int m0 = (blockIdx.x >> 2) * BM;
  const int n0 = (blockIdx.x & 3) * BN;
  const int ar  = tid >> 3;
  const int ak  = (tid & 7) * 4;
  const int bkr = tid >> 4;
  const int bn  = (tid & 15) * 4;
  const int tx = tid & 15;
  const int ty = tid >> 4;

  float acc[2][4] = {};
  float4 a0 = *(const float4*)(x + (size_t)(m0 + ar) * D_ + ak);
  float4 b0 = *(const float4*)(W + (size_t)bkr * H_ + n0 + bn);
  float4 b1 = *(const float4*)(W + (size_t)(bkr + 16) * H_ + n0 + bn);

  for (int kk = 0; kk < D_; kk += BK) {
    __syncthreads();
    As[ak + 0][ar] = a0.x; As[ak + 1][ar] = a0.y;
    As[ak + 2][ar] = a0.z; As[ak + 3][ar] = a0.w;
    *(float4*)&Bs[bkr][bn] = b0;
    *(float4*)&Bs[bkr + 16][bn] = b1;
    __syncthreads();
    if (kk + BK < D_) {
      a0 = *(const float4*)(x + (size_t)(m0 + ar) * D_ + kk + BK + ak);
      b0 = *(const float4*)(W + (size_t)(kk + BK + bkr) * H_ + n0 + bn);
      b1 = *(const float4*)(W + (size_t)(kk + BK + bkr + 16) * H_ + n0 + bn);
    }
#pragma unroll
    for (int k = 0; k < BK; ++k) {
      const float2 a = *(const float2*)&As[k][ty * 2];
      const float4 b = *(const float4*)&Bs[k][tx * 4];
      acc[0][0] = fmaf(a.x, b.x, acc[0][0]); acc[0][1] = fmaf(a.x, b.y, acc[0][1]);
      acc[0][2] = fmaf(a.x, b.z, acc[0][2]); acc[0][3] = fmaf(a.x, b.w, acc[0][3]);
      acc[1][0] = fmaf(a.y, b.x, acc[1][0]); acc[1][1] = fmaf(a.y, b.y, acc[1][1]);
      acc[1][2] = fmaf(a.y, b.z, acc[1][2]); acc[1][3] = fmaf(a.y, b.w, acc[1][3]);
    }
  }
#pragma unroll
  for (int i = 0; i < 2; ++i) {
    float4 v = {acc[i][0], acc[i][1], acc[i][2], acc[i][3]};
    *(float4*)(out + (size_t)(m0 + ty * 2 + i) * H_ + n0 + tx * 4) = v;
  }
}

// ---------------------------------------------------------------------------
// K4: layer-1 gather-aggregate + ReLU, and build pooled layer-2 weights w2:
//   x1[v,t] = relu( b1[t] + dv^2 h1[v,t] + sum_i (dv du_i) h1[u_i,t] )
//   w2[b(v), u_i] += dv*du_i  ; w2[b(v), v] += dv^2
// ---------------------------------------------------------------------------
__global__ __launch_bounds__(256) void k_agg(
    const float* __restrict__ h, const float* __restrict__ bias,
    const int* __restrict__ cnt, const int* __restrict__ bucket,
    float* __restrict__ out, float* __restrict__ w2) {
  __shared__ int   us[CAP];
  __shared__ float fs[CAP];
  const int v = blockIdx.x;
  const int t = threadIdx.x;
  const int deg = cnt[v];
  const float dv = rsqrtf(1.0f + (float)deg);
  const int m = deg > CAP ? CAP : deg;
  const int bg = v >> 7;                    // graph id
  if (t < m) {
    const int u = bucket[(size_t)v * CAP + t];
    const float f = dv * rsqrtf(1.0f + (float)cnt[u]);
    us[t] = u;
    fs[t] = f;
    atomicAdd(&w2[(size_t)bg * N_ + u], f);
  }
  if (t == 0) atomicAdd(&w2[(size_t)bg * N_ + v], dv * dv);
  __syncthreads();
  float acc = bias[t] + dv * dv * h[(size_t)v * H_ + t];
  int i = 0;
  for (; i + 4 <= m; i += 4) {
    const int u0 = us[i], u1 = us[i + 1], u2 = us[i + 2], u3 = us[i + 3];
    const float f0 = fs[i], f1 = fs[i + 1], f2 = fs[i + 2], f3 = fs[i + 3];
    const float h0 = h[(size_t)u0 * H_ + t];
    const float h1 = h[(size_t)u1 * H_ + t];
    const float h2 = h[(size_t)u2 * H_ + t];
    const float h3 = h[(size_t)u3 * H_ + t];
    acc = fmaf(f0, h0, acc); acc = fmaf(f1, h1, acc);
    acc = fmaf(f2, h2, acc); acc = fmaf(f3, h3, acc);
  }
  for (; i < m; ++i) acc = fmaf(fs[i], h[(size_t)us[i] * H_ + t], acc);
  out[(size_t)v * H_ + t] = fmaxf(acc, 0.f);
}

// ---------------------------------------------------------------------------
// K6: pooled output GEMM: out[b,t] = (1/NG) sum_u w2[b,u] h2[u,t] + b2[t]
//   block = (bgroup of BG graphs) x (u-chunk of UC rows); atomicAdd into out
// ---------------------------------------------------------------------------
__global__ __launch_bounds__(256) void k_out(
    const float* __restrict__ h2, const float* __restrict__ w2,
    const float* __restrict__ b2, float* __restrict__ outp) {
  __shared__ float wsh[BG][UC];
  const int nuc = N_ / UC;                  // 16
  const int bg = blockIdx.x / nuc;          // 0..7
  const int uc = blockIdx.x % nuc;          // 0..15
  const int t = threadIdx.x;
  const int u0 = uc * UC;
#pragma unroll
  for (int j = 0; j < BG; ++j)
    wsh[j][t] = w2[(size_t)(bg * BG + j) * N_ + u0 + t];
  __syncthreads();
  float acc[BG] = {};
#pragma unroll 4
  for (int i = 0; i < UC; ++i) {
    const float hv = h2[(size_t)(u0 + i) * H_ + t];
#pragma unroll
    for (int j = 0; j < BG; ++j) acc[j] = fmaf(wsh[j][i], hv, acc[j]);
  }
  const float inv = 1.0f / NG_;
  const float bias = (uc == 0) ? b2[t] : 0.f;
#pragma unroll
  for (int j = 0; j < BG; ++j)
    atomicAdd(&outp[(size_t)(bg * BG + j) * H_ + t], acc[j] * inv + bias);
}

extern "C" void kernel_launch(void* const* d_in, const int* in_sizes, int n_in,
                              void* d_out, int out_size, void* d_ws, size_t ws_size,
                              hipStream_t stream) {
  const float* emb  = (const float*)d_in[0];
  const int*   gids = (const int*)d_in[1];
  const int*   eidx = (const int*)d_in[2];
  const float* W1   = (const float*)d_in[3];
  const float* b1   = (const float*)d_in[4];
  const float* W2   = (const float*)d_in[5];
  const float* b2   = (const float*)d_in[6];
  float* out = (float*)d_out;

  const int* src = eidx;
  const int* dst = eidx + E_;

  // Workspace layout (floats)
  float* ws = (float*)d_ws;
  float* node_x = ws;                           // 4 MB
  float* hbuf   = node_x + (size_t)N_ * D_;     // 4 MB (h1, then reused h2? kept separate)
  float* x1     = hbuf   + (size_t)N_ * H_;     // 4 MB
  float* h2     = x1     + (size_t)N_ * H_;     // 4 MB
  float* w2     = h2     + (size_t)N_ * H_;     // 512 KB (B x N)
  int*   cnt    = (int*)(w2 + (size_t)B_ * N_); // 16 KB
  int*   bucket = cnt + N_;                     // 1 MB (N x CAP)

  // K1: node features + zero cnt/w2/out
  k_node_mean<<<N_, 64, 0, stream>>>(emb, gids, node_x, cnt, w2, out);

  // K2: adjacency buckets
  k_build<<<(E_ + 255) / 256, 256, 0, stream>>>(src, dst, cnt, bucket);

  // K3: h1 = node_x @ W1
  k_gemm<<<(N_ / BM) * (H_ / BN), 256, 0, stream>>>(node_x, W1, hbuf);

  // K4: x1 = relu(aggregate(h1)) ; build w2 pooled weights
  k_agg<<<N_, 256, 0, stream>>>(hbuf, b1, cnt, bucket, x1, w2);

  // K5: h2 = x1 @ W2
  k_gemm<<<(N_ / BM) * (H_ / BN), 256, 0, stream>>>(x1, W2, h2);

  // K6: out = (1/NG) * w2 @ h2 + b2
  k_out<<<(B_ / BG) * (N_ / UC), 256, 0, stream>>>(h2, w2, b2, out);
}